// Round 14
// baseline (177.239 us; speedup 1.0000x reference)
//
#include <hip/hip_runtime.h>
#include <stdint.h>
#include <float.h>

#define N_   384
#define NB   768
typedef unsigned short u16;
typedef unsigned int   u32;
typedef __attribute__((ext_vector_type(8))) short short8;   // 8 bf16 (4 VGPRs)
typedef __attribute__((ext_vector_type(4))) float f32x4;    // MFMA accumulator

__device__ __forceinline__ u32 f2bf(float x){
  union{float f; u32 u;} v; v.f = x;
  return (v.u + 0x7fffu + ((v.u >> 16) & 1u)) >> 16;   // RNE bf16
}
__device__ __forceinline__ float bf2f(u16 s){
  union{u32 u; float f;} v; v.u = ((u32)s) << 16; return v.f;
}
__device__ __forceinline__ u32 packbf(float a, float b){
  return f2bf(a) | (f2bf(b) << 16);
}
__device__ __forceinline__ uint4 pack8(const float* f){
  uint4 u;
  u.x = packbf(f[0],f[1]); u.y = packbf(f[2],f[3]);
  u.z = packbf(f[4],f[5]); u.w = packbf(f[6],f[7]);
  return u;
}
__device__ __forceinline__ void unpack8(uint4 u, float* f){
  u32 w[4] = {u.x, u.y, u.z, u.w};
  #pragma unroll
  for (int q = 0; q < 4; ++q){
    union{u32 u; float f;} lo, hi;
    lo.u = w[q] << 16; hi.u = w[q] & 0xffff0000u;
    f[2*q] = lo.f; f[2*q+1] = hi.f;
  }
}
// element index into a [rows][128] bf16 tile, 16B-granule XOR swizzle
__device__ __forceinline__ int swze(int row, int k){
  return row*128 + (((k >> 3) ^ (row & 7)) << 3) + (k & 7);
}

// ---------------- qk = x @ W_qk + b_qk  (bf16 out) ----------------
__global__ __launch_bounds__(256) void qk_kernel(
    const float* __restrict__ x, const float* __restrict__ Wqk,
    const float* __restrict__ bqk, u16* __restrict__ qkbf)
{
  __shared__ float xs[4][128];
  const int r0 = blockIdx.x * 4;
  const int t = threadIdx.x;
  for (int idx = t; idx < 512; idx += 256){
    int r = idx >> 7, k = idx & 127;
    xs[r][k] = x[(size_t)(r0 + r)*128 + k];
  }
  __syncthreads();
  float acc[4][2];
  #pragma unroll
  for (int r = 0; r < 4; ++r){ acc[r][0] = bqk[t]; acc[r][1] = bqk[t + 256]; }
  #pragma unroll 4
  for (int k = 0; k < 128; ++k){
    float w0 = Wqk[(size_t)k*512 + t], w1 = Wqk[(size_t)k*512 + t + 256];
    #pragma unroll
    for (int r = 0; r < 4; ++r){
      acc[r][0] = fmaf(xs[r][k], w0, acc[r][0]);
      acc[r][1] = fmaf(xs[r][k], w1, acc[r][1]);
    }
  }
  #pragma unroll
  for (int r = 0; r < 4; ++r){
    qkbf[(size_t)(r0+r)*512 + t]       = (u16)f2bf(acc[r][0]);
    qkbf[(size_t)(r0+r)*512 + t + 256] = (u16)f2bf(acc[r][1]);
  }
}

// =====================================================================
// ===================== PRIMARY (split) PATH ==========================
// =====================================================================

// fragment-major weight pack: frag (fc,ks): lane l holds W[k=ks*32+(l>>4)*8+e][c=fc*16+(l&15)]
__global__ __launch_bounds__(256) void prep_frag(
    const float* __restrict__ We, const float* __restrict__ Wedge,
    const float* __restrict__ Wc1, u16* __restrict__ WeF,
    u16* __restrict__ WgF, u16* __restrict__ W1F)
{
  const int id = blockIdx.x*256 + threadIdx.x;   // 28 blocks * 256 = 7168 = 112 frags * 64
  const int frag = id >> 6, lane = id & 63;
  if (frag >= 112) return;
  const float* src; u16* dst; int C, fc, ks;
  if (frag < 64){       fc = frag >> 2;      ks = frag & 3; src = We;    C = 256; dst = WeF + (size_t)frag*512; }
  else if (frag < 80){  int fr = frag - 64; fc = fr >> 2;   ks = fr & 3; src = Wedge; C = 64;  dst = WgF + (size_t)fr*512; }
  else {                int fr = frag - 80; fc = fr >> 2;   ks = fr & 3; src = Wc1;   C = 128; dst = W1F + (size_t)fr*512; }
  const int c = fc*16 + (lane & 15);
  const int kb = ks*32 + (lane >> 4)*8;
  float f[8];
  #pragma unroll
  for (int e = 0; e < 8; ++e) f[e] = src[(size_t)(kb + e)*C + c];
  *(uint4*)(dst + lane*8) = pack8(f);
}

// ---------------- replicate weight images 8x (L2-hotspot spreading) ----------------
__global__ __launch_bounds__(256) void prep_rep(
    const u16* __restrict__ WeF, const u16* __restrict__ WgF,
    const u16* __restrict__ W1F, uint4* __restrict__ WeR,
    uint4* __restrict__ WgR, uint4* __restrict__ W1R)
{
  const int id = blockIdx.x*256 + threadIdx.x;   // 224 blocks * 256 = 57344
  if (id < 32768)       WeR[id] = ((const uint4*)WeF)[id & 4095];
  else if (id < 40960)  WgR[id - 32768] = ((const uint4*)WgF)[(id - 32768) & 1023];
  else if (id < 57344)  W1R[id - 40960] = ((const uint4*)W1F)[(id - 40960) & 2047];
}

// ---------------- K1L: dual-tile swapped e-GEMM, weights in LDS ----------------
// R13 structure; weight source selected from 8 replicas by block id (rmask).
__global__ __launch_bounds__(256, 2) void k1L_logits_ev(
    const float* __restrict__ coor, const float* __restrict__ edge_attr,
    const float* __restrict__ be, const int* __restrict__ emask,
    const u16* __restrict__ qkbf, const u16* __restrict__ WeFb, int rmask,
    u16* __restrict__ attL, u16* __restrict__ evG)
{
  __shared__ u16 WeL[32768];   // 64 KB: 64 frags x 512 u16
  const int t = threadIdx.x;
  const int ch = blockIdx.x, bi = blockIdx.y;     // ch: 0..2 (128-j blocks)
  const int b = (bi >= N_) ? 1 : 0;
  const int w = t >> 6, l = t & 63, lr = l & 15, kg = l >> 4;
  const int jw = ch*128 + w*32;
  const int ja0 = jw + lr, ja1 = jw + 16 + lr;
  const u16* WeF = WeFb + ((size_t)((bi*3 + ch) & rmask) << 15);   // 32768 u16/copy

  // ---- HOISTED epilogue gathers: in flight under staging + MFMA ----
  const int mk0 = emask[(size_t)bi*N_ + ja0];
  const int mk1 = emask[(size_t)bi*N_ + ja1];
  uint2 rmu0[8], rmu1[8], lmu[8];
  float4 bevA[8];
  #pragma unroll
  for (int mf = 0; mf < 8; ++mf){
    const int c = mf*16 + kg*4;
    lmu[mf]  = *(const uint2*)&qkbf[(size_t)bi*512 + c];
    rmu0[mf] = *(const uint2*)&qkbf[(size_t)(b*N_+ja0)*512 + 128 + c];
    rmu1[mf] = *(const uint2*)&qkbf[(size_t)(b*N_+ja1)*512 + 128 + c];
    bevA[mf] = *(const float4*)&be[c];
  }

  // ---- edge fragments for both tiles (lane: 16-idx = j, k = kg*8+e) ----
  short8 afr0[4], afr1[4];
  {
    const float cix = coor[bi*3], ciy = coor[bi*3+1], ciz = coor[bi*3+2];
    const float* s0 = &edge_attr[((size_t)bi*N_ + ja0)*64 + kg*8];
    const float* s1 = &edge_attr[((size_t)bi*N_ + ja1)*64 + kg*8];
    #pragma unroll
    for (int ks = 0; ks < 2; ++ks){
      float4 a  = *(const float4*)(s0 + ks*32);
      float4 c4 = *(const float4*)(s0 + ks*32 + 4);
      float f[8] = {a.x,a.y,a.z,a.w,c4.x,c4.y,c4.z,c4.w};
      *(uint4*)&afr0[ks] = pack8(f);
      a  = *(const float4*)(s1 + ks*32);
      c4 = *(const float4*)(s1 + ks*32 + 4);
      float g[8] = {a.x,a.y,a.z,a.w,c4.x,c4.y,c4.z,c4.w};
      *(uint4*)&afr1[ks] = pack8(g);
    }
    float dx = cix - coor[(size_t)(b*N_+ja0)*3+0];
    float dy = ciy - coor[(size_t)(b*N_+ja0)*3+1];
    float dz = ciz - coor[(size_t)(b*N_+ja0)*3+2];
    const float dm0 = fminf(sqrtf(dx*dx + dy*dy + dz*dz), 2.0f);
    dx = cix - coor[(size_t)(b*N_+ja1)*3+0];
    dy = ciy - coor[(size_t)(b*N_+ja1)*3+1];
    dz = ciz - coor[(size_t)(b*N_+ja1)*3+2];
    const float dm1 = fminf(sqrtf(dx*dx + dy*dy + dz*dz), 2.0f);
    #pragma unroll
    for (int ks = 2; ks < 4; ++ks){
      const int g0 = (ks-2)*32 + kg*8;
      float f[8], g[8];
      #pragma unroll
      for (int e = 0; e < 8; ++e){
        const float x0 = (float)(g0+e)*(2.0f/63.0f);
        const float d0 = dm0 - x0, d1 = dm1 - x0;
        f[e] = __expf(-496.125f * d0 * d0);   // coeff = -0.5/(2/63)^2
        g[e] = __expf(-496.125f * d1 * d1);
      }
      *(uint4*)&afr0[ks] = pack8(f);
      *(uint4*)&afr1[ks] = pack8(g);
    }
  }

  // ---- stage WeF into LDS (64 KB, coalesced) ----
  for (int idx = t; idx < 4096; idx += 256)
    ((uint4*)WeL)[idx] = ((const uint4*)WeF)[idx];
  __syncthreads();

  // ---- group A: e_m channels (fc 0..7) -> logits for both tiles ----
  f32x4 a0[8], a1[8];
  #pragma unroll
  for (int f = 0; f < 8; ++f){ a0[f] = (f32x4){0.f,0.f,0.f,0.f}; a1[f] = (f32x4){0.f,0.f,0.f,0.f}; }
  #pragma unroll
  for (int ks = 0; ks < 4; ++ks){
    #pragma unroll
    for (int mf = 0; mf < 8; ++mf){
      short8 wv = *(const short8*)&WeL[((mf*4 + ks)*64 + l)*8];
      a0[mf] = __builtin_amdgcn_mfma_f32_16x16x32_bf16(wv, afr0[ks], a0[mf], 0, 0, 0);
      a1[mf] = __builtin_amdgcn_mfma_f32_16x16x32_bf16(wv, afr1[ks], a1[mf], 0, 0, 0);
    }
  }
  #pragma unroll
  for (int tile = 0; tile < 2; ++tile){
    const int ja = tile ? ja1 : ja0;
    const f32x4* ac = tile ? a1 : a0;
    const int mk = tile ? mk1 : mk0;
    float s8[8];
    #pragma unroll
    for (int mf = 0; mf < 8; ++mf){
      const uint2 rmuv = tile ? rmu1[mf] : rmu0[mf];
      const u16* lmp = (const u16*)&lmu[mf];
      const u16* rmp = (const u16*)&rmuv;
      float s = 0.f;
      #pragma unroll
      for (int r = 0; r < 4; ++r){
        float e = ac[mf][r] + (&bevA[mf].x)[r]; e = e > 0.f ? e : 0.01f*e;
        s += e * bf2f(lmp[r]) * bf2f(rmp[r]);
      }
      s += __shfl_xor(s, 16); s += __shfl_xor(s, 32);
      s8[mf] = s * 0.25f;
    }
    if (kg == 0){
      const u32 NEG2 = packbf(-1e30f, -1e30f);
      uint4 o;
      o.x = mk ? packbf(s8[0], s8[1]) : NEG2;
      o.y = mk ? packbf(s8[2], s8[3]) : NEG2;
      o.z = mk ? packbf(s8[4], s8[5]) : NEG2;
      o.w = mk ? packbf(s8[6], s8[7]) : NEG2;
      *(uint4*)&attL[(size_t)bi*3072 + ja*8] = o;
    }
  }

  // ---- group B: e_v channels (fc 8..15) -> DIRECT swizzled global stores ----
  #pragma unroll
  for (int f = 0; f < 8; ++f){ a0[f] = (f32x4){0.f,0.f,0.f,0.f}; a1[f] = (f32x4){0.f,0.f,0.f,0.f}; }
  #pragma unroll
  for (int ks = 0; ks < 4; ++ks){
    #pragma unroll
    for (int mf = 0; mf < 8; ++mf){
      short8 wv = *(const short8*)&WeL[(((8+mf)*4 + ks)*64 + l)*8];
      a0[mf] = __builtin_amdgcn_mfma_f32_16x16x32_bf16(wv, afr0[ks], a0[mf], 0, 0, 0);
      a1[mf] = __builtin_amdgcn_mfma_f32_16x16x32_bf16(wv, afr1[ks], a1[mf], 0, 0, 0);
    }
  }
  #pragma unroll
  for (int tile = 0; tile < 2; ++tile){
    const f32x4* ac = tile ? a1 : a0;
    const int jl = w*32 + tile*16 + lr;          // 0..127 within block
    const int chunk = ch*2 + (jl >> 6);          // 64-j chunk index
    const int row = jl & 63;
    u16* dstb = evG + ((size_t)bi*6 + chunk)*8192 + row*128;
    #pragma unroll
    for (int mf = 0; mf < 8; ++mf){
      const int c = mf*16 + kg*4;                // c within [0,128) of the e_v half
      float4 bev = *(const float4*)&be[128 + c];
      float e[4];
      #pragma unroll
      for (int r = 0; r < 4; ++r){
        float y = ac[mf][r] + (&bev.x)[r]; e[r] = y > 0.f ? y : 0.01f*y;
      }
      uint2 pk; pk.x = packbf(e[0], e[1]); pk.y = packbf(e[2], e[3]);
      const int g = c >> 3;
      *(uint2*)&dstb[((g ^ (row & 7)) << 3) + (kg & 1)*4] = pk;
    }
  }
}

// ---------------- K2: softmax over j, probs bf16 in place ----------------
__global__ __launch_bounds__(512) void k2_softmax(u16* __restrict__ attL)
{
  __shared__ u16 sl[3072];
  const int t = threadIdx.x, bi = blockIdx.x;
  uint4* sl4 = (uint4*)sl;
  if (t < 384) sl4[t] = ((const uint4*)(attL + (size_t)bi*3072))[t];
  __syncthreads();
  const int h = t >> 6, lane = t & 63;
  float v[6]; float m = -FLT_MAX;
  #pragma unroll
  for (int q = 0; q < 6; ++q){ v[q] = bf2f(sl[(lane + q*64)*8 + h]); m = fmaxf(m, v[q]); }
  #pragma unroll
  for (int o = 32; o >= 1; o >>= 1) m = fmaxf(m, __shfl_xor(m, o));
  float s = 0.f;
  #pragma unroll
  for (int q = 0; q < 6; ++q){ v[q] = __expf(v[q] - m); s += v[q]; }
  #pragma unroll
  for (int o = 32; o >= 1; o >>= 1) s += __shfl_xor(s, o);
  const float inv = 1.f / s;
  #pragma unroll
  for (int q = 0; q < 6; ++q) sl[(lane + q*64)*8 + h] = (u16)f2bf(v[q] * inv);
  __syncthreads();
  if (t < 384) ((uint4*)(attL + (size_t)bi*3072))[t] = sl4[t];
}

// ---------------- K3L: swapped edge+c1 GEMM, weights in LDS ----------------
__global__ __launch_bounds__(256, 3) void k3L_edge_c1(
    const float* __restrict__ bedge, const float* __restrict__ bc1,
    const float* __restrict__ Wc2, const u16* __restrict__ qkbf,
    const u16* __restrict__ WgFb, const u16* __restrict__ W1Fb, int rmask,
    const u16* __restrict__ attL, float* __restrict__ edge_out,
    float* __restrict__ cattB)
{
  __shared__ u16 WL[24576];   // 48 KB: Wg 16 frags (8192 u16) + W1 32 frags (16384 u16)
  const int t = threadIdx.x, ch = blockIdx.x, bi = blockIdx.y;
  const int b = (bi >= N_) ? 1 : 0;
  const int j0 = ch * 64;
  const int w = t >> 6, l = t & 63, lr = l & 15, kg = l >> 4;
  const int jloc = w*16 + lr;
  const int jglob = j0 + jloc;
  const u16* evS = (const u16*)edge_out + ((size_t)bi*6 + ch)*8192;
  const int rep = (bi*6 + ch) & rmask;
  const u16* WgF = WgFb + ((size_t)rep << 13);   // 8192 u16/copy
  const u16* W1F = W1Fb + ((size_t)rep << 14);   // 16384 u16/copy

  for (int idx = t; idx < 3072; idx += 256)
    ((uint4*)WL)[idx] = (idx < 1024) ? ((const uint4*)WgF)[idx]
                                     : ((const uint4*)W1F)[idx - 1024];
  __syncthreads();
  const u16* WgL = WL;
  const u16* W1L = WL + 8192;

  f32x4 eacc[4], cacc[8];
  #pragma unroll
  for (int f = 0; f < 4; ++f) eacc[f] = (f32x4){0.f,0.f,0.f,0.f};
  #pragma unroll
  for (int f = 0; f < 8; ++f) cacc[f] = (f32x4){0.f,0.f,0.f,0.f};

  #pragma unroll
  for (int ks = 0; ks < 4; ++ks){
    const int k0 = ks*32 + kg*8;
    short8 ar = *(const short8*)&evS[swze(jloc, k0)];
    const float p = bf2f(attL[(size_t)bi*3072 + jglob*8 + (k0 >> 4)]);
    uint4 rvu = *(const uint4*)&qkbf[(size_t)(b*N_ + jglob)*512 + 384 + k0];
    uint4 lvu = *(const uint4*)&qkbf[(size_t)bi*512 + 256 + k0];
    short8 ame, amc;
    const u16* arp = (const u16*)&ar;
    const u16* rvp = (const u16*)&rvu;
    const u16* lvp = (const u16*)&lvu;
    u16* amep = (u16*)&ame; u16* amcp = (u16*)&amc;
    #pragma unroll
    for (int e = 0; e < 8; ++e){
      const float ef = bf2f(arp[e]) * p;
      amep[e] = (u16)f2bf(ef);
      amcp[e] = (u16)f2bf(ef * bf2f(lvp[e]) * bf2f(rvp[e]));
    }
    #pragma unroll
    for (int f = 0; f < 4; ++f){
      short8 wv = *(const short8*)&WgL[((f*4 + ks)*64 + l)*8];
      eacc[f] = __builtin_amdgcn_mfma_f32_16x16x32_bf16(wv, ame, eacc[f], 0, 0, 0);
    }
    #pragma unroll
    for (int f = 0; f < 8; ++f){
      short8 wv = *(const short8*)&W1L[((f*4 + ks)*64 + l)*8];
      cacc[f] = __builtin_amdgcn_mfma_f32_16x16x32_bf16(wv, amc, cacc[f], 0, 0, 0);
    }
  }
  // edge epilogue: D[g, j] -> lane j fixed, g = gf*16 + kg*4 + r -> float4 stores
  #pragma unroll
  for (int gf = 0; gf < 4; ++gf){
    const int g0 = gf*16 + kg*4;
    float4 bg = *(const float4*)&bedge[g0];
    float4 o;
    o.x = eacc[gf][0] + bg.x; o.y = eacc[gf][1] + bg.y;
    o.z = eacc[gf][2] + bg.z; o.w = eacc[gf][3] + bg.w;
    *(float4*)&edge_out[((size_t)bi*N_ + jglob)*64 + g0] = o;
  }
  // c1 epilogue: lane-local 32 terms + 2 shfl
  {
    float s = 0.f;
    #pragma unroll
    for (int cf = 0; cf < 8; ++cf){
      const int c0 = cf*16 + kg*4;
      float4 b1 = *(const float4*)&bc1[c0];
      float4 w2 = *(const float4*)&Wc2[c0];
      #pragma unroll
      for (int r = 0; r < 4; ++r){
        float y = cacc[cf][r] + (&b1.x)[r]; y = y > 0.f ? y : 0.01f*y;
        s += y * (&w2.x)[r];
      }
    }
    s += __shfl_xor(s, 16); s += __shfl_xor(s, 32);
    if (kg == 0) cattB[(size_t)bi*N_ + jglob] = s;
  }
}

// ---------------- K4: node einsum (vectorized) + W_node + coor finale ----------------
__global__ __launch_bounds__(256) void k4_node_coor(
    const float* __restrict__ coor, const float* __restrict__ Wnode,
    const float* __restrict__ bnode, const float* __restrict__ bc2,
    const int* __restrict__ emask, const int* __restrict__ fmask,
    const u16* __restrict__ qkbf, const u16* __restrict__ attL,
    const float* __restrict__ cattB, float* __restrict__ node_out,
    float* __restrict__ coor_out)
{
  __shared__ u16 pS[3072];
  __shared__ float part[8][256];
  __shared__ float red[256];
  __shared__ float halfb[256];
  __shared__ float cred[16];
  const int t = threadIdx.x, bi = blockIdx.x;
  const int b = (bi >= N_) ? 1 : 0;
  for (int idx = t; idx < 384; idx += 256)
    ((uint4*)pS)[idx] = ((const uint4*)(attL + (size_t)bi*3072))[idx];
  __syncthreads();
  // node pre: 32 chan-groups (uint4) x 8 j-groups of 48 j
  {
    const int q = t & 31, jg = t >> 5;
    const int ch0 = 256 + q*8;
    const int h = (q < 16) ? (q >> 1) : ((q - 16) >> 1);
    const int slot0 = (q < 16) ? (h*32 + (q & 1)*8) : (h*32 + 16 + (q & 1)*8);
    float a8[8];
    #pragma unroll
    for (int e = 0; e < 8; ++e) a8[e] = 0.f;
    for (int j = jg*48; j < jg*48 + 48; ++j){
      const float p = bf2f(pS[j*8 + h]);
      uint4 v = *(const uint4*)&qkbf[(size_t)(b*N_+j)*512 + ch0];
      const u16* vp = (const u16*)&v;
      #pragma unroll
      for (int e = 0; e < 8; ++e) a8[e] = fmaf(p, bf2f(vp[e]), a8[e]);
    }
    float4 o0 = {a8[0],a8[1],a8[2],a8[3]}, o1 = {a8[4],a8[5],a8[6],a8[7]};
    *(float4*)&part[jg][slot0]     = o0;
    *(float4*)&part[jg][slot0 + 4] = o1;
  }
  __syncthreads();
  {
    float s = 0.f;
    #pragma unroll
    for (int g = 0; g < 8; ++g) s += part[g][t];
    red[t] = s;
  }
  __syncthreads();
  {
    const int c = t & 127, qq = t >> 7;
    float s = 0.f;
    #pragma unroll 4
    for (int k = qq*128; k < qq*128 + 128; ++k)
      s = fmaf(red[k], Wnode[(size_t)k*128 + c], s);
    halfb[t] = s;
  }
  __syncthreads();
  if (t < 128)
    node_out[(size_t)bi*128 + t] = halfb[t] + halfb[128 + t] + bnode[t];

  // coor
  {
    const float cix = coor[bi*3], ciy = coor[bi*3+1], ciz = coor[bi*3+2];
    float vx=0.f, vy=0.f, vz=0.f, cnt=0.f;
    for (int j = t; j < N_; j += 256){
      if (emask[(size_t)bi*N_ + j]){
        cnt += 1.f;
        const float val = cattB[(size_t)bi*N_ + j] + bc2[0];
        const float dx = cix - coor[(size_t)(b*N_+j)*3+0];
        const float dy = ciy - coor[(size_t)(b*N_+j)*3+1];
        const float dz = ciz - coor[(size_t)(b*N_+j)*3+2];
        const float nrm = sqrtf(dx*dx + dy*dy + dz*dz);
        if (nrm > 0.f){
          const float qv = val / fmaxf(nrm, 1e-8f);
          vx += qv*dx; vy += qv*dy; vz += qv*dz;
        }
      }
    }
    #pragma unroll
    for (int o = 32; o >= 1; o >>= 1){
      vx += __shfl_xor(vx, o); vy += __shfl_xor(vy, o);
      vz += __shfl_xor(vz, o); cnt += __shfl_xor(cnt, o);
    }
    const int w = t >> 6, l = t & 63;
    if (l == 0){ cred[w*4]=vx; cred[w*4+1]=vy; cred[w*4+2]=vz; cred[w*4+3]=cnt; }
  }
  __syncthreads();
  if (t == 0){
    float sx=0.f, sy=0.f, sz=0.f, sc=0.f;
    #pragma unroll
    for (int ww = 0; ww < 4; ++ww){
      sx += cred[ww*4]; sy += cred[ww*4+1]; sz += cred[ww*4+2]; sc += cred[ww*4+3];
    }
    const float d = sc + 1e-7f, fm = (float)fmask[bi];
    coor_out[bi*3+0] = sx/d*fm;
    coor_out[bi*3+1] = sy/d*fm;
    coor_out[bi*3+2] = sz/d*fm;
  }
}

// =====================================================================
// ================= FALLBACK (R3 monolithic) PATH =====================
// =====================================================================

__global__ __launch_bounds__(512) void prep_wt(
    const float* __restrict__ We, const float* __restrict__ Wedge,
    const float* __restrict__ Wc1, u16* __restrict__ WeT,
    u16* __restrict__ WgT, u16* __restrict__ Wc1T)
{
  const int id = blockIdx.x*512 + threadIdx.x;
  const float* src; u16* dst; int c, g, stride;
  if (id < 4096){        int q = id;      c = q>>4; g = q&15; src = We    + (size_t)g*8*256 + c; stride = 256; dst = WeT  + c*128 + ((g ^ (c&7))<<3); }
  else if (id < 5120){   int q = id-4096; c = q>>4; g = q&15; src = Wedge + (size_t)g*8*64  + c; stride = 64;  dst = WgT  + c*128 + ((g ^ (c&7))<<3); }
  else if (id < 7168){   int q = id-5120; c = q>>4; g = q&15; src = Wc1   + (size_t)g*8*128 + c; stride = 128; dst = Wc1T + c*128 + ((g ^ (c&7))<<3); }
  else return;
  float f[8];
  #pragma unroll
  for (int e = 0; e < 8; ++e) f[e] = src[(size_t)e*stride];
  *(uint4*)dst = pack8(f);
}

#define L_ATT   0
#define L_AS    12288
#define L_WE    45056
#define L_WG    45056
#define L_W1    61440
#define L_PART  94208
#define L_EVP   110592
#define L_CATT  110592
#define L_RED2  113664
#define L_MISC  126976
#define L_QIF   127488
#define L_TOTAL 129536

__global__ __launch_bounds__(512, 1) void se3_fused(
    const float* __restrict__ coor, const float* __restrict__ edge_attr,
    const float* __restrict__ be, const float* __restrict__ bedge,
    const float* __restrict__ Wnode, const float* __restrict__ bnode,
    const float* __restrict__ bc1, const float* __restrict__ Wc2,
    const float* __restrict__ bc2, const int* __restrict__ emask,
    const int* __restrict__ fmask, const u16* __restrict__ qkbf,
    const u16* __restrict__ WeTg, const u16* __restrict__ WgTg,
    const u16* __restrict__ Wc1Tg,
    float* __restrict__ node_out, float* __restrict__ edge_out, float* __restrict__ coor_out)
{
  extern __shared__ char smem[];
  float* att  = (float*)(smem + L_ATT);
  float* qif  = (float*)(smem + L_QIF);
  float* misc = (float*)(smem + L_MISC);

  const int t  = threadIdx.x;
  const int bi = blockIdx.x;
  const int b  = (bi >= N_) ? 1 : 0;
  const float cix = coor[bi*3], ciy = coor[bi*3+1], ciz = coor[bi*3+2];

  const int w  = t >> 6, l = t & 63;
  const int chh = w >> 2, jsb = (w & 3) * 16;
  const int lr = l & 15, kg = l >> 4;

  for (int idx = t; idx < 4096; idx += 512)
    ((uint4*)(smem + L_WE))[idx] = ((const uint4*)WeTg)[idx];
  qif[t] = bf2f(qkbf[(size_t)bi*512 + t]);
  __syncthreads();

  float bevf[8], lmvf[8];
  #pragma unroll
  for (int f = 0; f < 8; ++f){
    const int c = chh*128 + f*16 + lr;
    bevf[f] = be[c];
    lmvf[f] = (chh == 0) ? qif[c] : 0.f;
  }

  float4 pa0, pb0, pa1, pb1;
  const int gq = t & 15, rq = t >> 4;
  auto issue_ea = [&](int j0){
    if (gq < 8){
      const float* s0 = &edge_attr[((size_t)bi*N_ + j0 + rq)*64 + gq*8];
      const float* s1 = &edge_attr[((size_t)bi*N_ + j0 + rq + 32)*64 + gq*8];
      pa0 = *(const float4*)s0; pb0 = *(const float4*)(s0 + 4);
      pa1 = *(const float4*)s1; pb1 = *(const float4*)(s1 + 4);
    }
  };

  uint4* evg = (uint4*)(edge_out + (size_t)bi*24576);

  issue_ea(0);
  for (int ch = 0; ch < 6; ++ch){
    const int j0 = ch * 64;
    {
      u16* As = (u16*)(smem + L_AS + (ch & 1)*16384);
      #pragma unroll
      for (int q = 0; q < 2; ++q){
        const int row = rq + q*32;
        const int j = j0 + row;
        float f[8];
        if (gq < 8){
          float4 A = q ? pa1 : pa0, Bv = q ? pb1 : pb0;
          f[0]=A.x; f[1]=A.y; f[2]=A.z; f[3]=A.w;
          f[4]=Bv.x; f[5]=Bv.y; f[6]=Bv.z; f[7]=Bv.w;
        } else {
          const float dx = cix - coor[(size_t)(b*N_+j)*3+0];
          const float dy = ciy - coor[(size_t)(b*N_+j)*3+1];
          const float dz = ciz - coor[(size_t)(b*N_+j)*3+2];
          const float dm = fminf(sqrtf(dx*dx + dy*dy + dz*dz), 2.0f);
          const int k0 = (gq - 8)*8;
          #pragma unroll
          for (int e = 0; e < 8; ++e){
            const float dd = dm - (float)(k0+e)*(2.0f/63.0f);
            f[e] = __expf(-496.125f * dd * dd);
          }
        }
        ((uint4*)As)[row*16 + (gq ^ (row & 7))] = pack8(f);
      }
    }
    __syncthreads();
    if (ch + 1 < 6) issue_ea((ch+1)*64);

    f32x4 acc[8];
    #pragma unroll
    for (int f = 0; f < 8; ++f) acc[f] = (f32x4){0.f,0.f,0.f,0.f};
    {
      u16* As  = (u16*)(smem + L_AS + (ch & 1)*16384);
      u16* WeL = (u16*)(smem + L_WE);
      #pragma unroll
      for (int ks = 0; ks < 4; ++ks){
        const int k0 = ks*32 + kg*8;
        short8 a = *(const short8*)&As[swze(jsb + lr, k0)];
        #pragma unroll
        for (int f = 0; f < 8; ++f){
          const int c = chh*128 + f*16 + lr;
          short8 bb = *(const short8*)&WeL[swze(c, k0)];
          acc[f] = __builtin_amdgcn_mfma_f32_16x16x32_bf16(a, bb, acc[f], 0, 0, 0);
        }
      }
    }
    if (chh == 0){
      #pragma unroll
      for (int f = 0; f < 8; ++f){
        #pragma unroll
        for (int r = 0; r < 4; ++r){
          const int j = j0 + jsb + kg*4 + r;
          float e = acc[f][r] + bevf[f]; e = e > 0.f ? e : 0.01f*e;
          const float rm = bf2f(qkbf[(size_t)(b*N_+j)*512 + 128 + f*16 + lr]);
          float s = lmvf[f] * rm * e;
          s += __shfl_xor(s, 1); s += __shfl_xor(s, 2);
          s += __shfl_xor(s, 4); s += __shfl_xor(s, 8);
          if (lr == 0)
            att[j*8 + f] = emask[(size_t)bi*N_ + j] ? s*0.25f : -FLT_MAX;
        }
      }
    } else {
      u16* Evp = (u16*)(smem + L_EVP);
      #pragma unroll
      for (int f = 0; f < 8; ++f){
        #pragma unroll
        for (int r = 0; r < 4; ++r){
          float e = acc[f][r] + bevf[f]; e = e > 0.f ? e : 0.01f*e;
          const float pr = __shfl_xor(e, 1);
          if (!(lr & 1)){
            const int jl = jsb + kg*4 + r;
            const int cv = f*16 + lr;
            *(u32*)&Evp[jl*128 + (((cv>>3) ^ (jl&7))<<3) + (cv&7)] = packbf(e, pr);
          }
        }
      }
    }
    __syncthreads();
    {
      const uint4* Evp4 = (const uint4*)(smem + L_EVP);
      #pragma unroll
      for (int q = 0; q < 2; ++q)
        evg[ch*1024 + t + q*512] = Evp4[t + q*512];
    }
  }

  {
    const int h = w, lane = l;
    float m = -FLT_MAX;
    #pragma unroll
    for (int q = 0; q < 6; ++q) m = fmaxf(m, att[(lane + q*64)*8 + h]);
    #pragma unroll
    for (int o = 32; o >= 1; o >>= 1) m = fmaxf(m, __shfl_xor(m, o));
    float pv[6], s = 0.f;
    #pragma unroll
    for (int q = 0; q < 6; ++q){ float p = __expf(att[(lane + q*64)*8 + h] - m); pv[q] = p; s += p; }
    #pragma unroll
    for (int o = 32; o >= 1; o >>= 1) s += __shfl_xor(s, o);
    const float inv = 1.f / s;
    #pragma unroll
    for (int q = 0; q < 6; ++q) att[(lane + q*64)*8 + h] = pv[q] * inv;
  }

  for (int idx = t; idx < 1024; idx += 512)
    ((uint4*)(smem + L_WG))[idx] = ((const uint4*)WgTg)[idx];
  for (int idx = t; idx < 2048; idx += 512){
    const int c = idx >> 4, g = idx & 15;
    uint4 u = ((const uint4*)Wc1Tg)[idx];
    const int k0 = ((g ^ (c & 7)) << 3);
    float f[8]; unpack8(u, f);
    #pragma unroll
    for (int e = 0; e < 8; ++e) f[e] *= qif[256 + k0 + e];
    ((uint4*)(smem + L_W1))[idx] = pack8(f);
  }

  float bgv[2], bc1v[4], w2v[4];
  #pragma unroll
  for (int f = 0; f < 2; ++f) bgv[f] = bedge[chh*32 + f*16 + lr];
  #pragma unroll
  for (int f = 0; f < 4; ++f){
    const int c2 = chh*64 + f*16 + lr;
    bc1v[f] = bc1[c2]; w2v[f] = Wc2[c2];
  }

  uint4 eva, evb;
  auto issue_ev = [&](int ch){
    eva = evg[ch*1024 + t];
    evb = evg[ch*1024 + t + 512];
  };
  issue_ev(0);
  __syncthreads();

  float* catt = (float*)(smem + L_CATT);

  for (int ch = 0; ch < 6; ++ch){
    const int j0 = ch * 64;
    {
      uint4* Ev4 = (uint4*)(smem + L_AS + (ch & 1)*16384);
      Ev4[t] = eva; Ev4[t + 512] = evb;
    }
    if (ch + 1 < 6) issue_ev(ch + 1);
    __syncthreads();

    u16* Ev  = (u16*)(smem + L_AS + (ch & 1)*16384);
    u16* WgL = (u16*)(smem + L_WG);
    u16* W1L = (u16*)(smem + L_W1);
    const int jrow = j0 + jsb + lr;

    f32x4 eacc[2], cacc[4];
    eacc[0] = (f32x4){0.f,0.f,0.f,0.f}; eacc[1] = (f32x4){0.f,0.f,0.f,0.f};
    #pragma unroll
    for (int f = 0; f < 4; ++f) cacc[f] = (f32x4){0.f,0.f,0.f,0.f};

    #pragma unroll
    for (int ks = 0; ks < 4; ++ks){
      const int k0 = ks*32 + kg*8;
      short8 ar = *(const short8*)&Ev[swze(jsb + lr, k0)];
      const float p = att[jrow*8 + (k0 >> 4)];
      uint4 rvu = *(const uint4*)&qkbf[(size_t)(b*N_+jrow)*512 + 384 + k0];
      short8 ame, amc;
      const u16* arp = (const u16*)&ar; const u16* rvp = (const u16*)&rvu;
      u16* amep = (u16*)&ame; u16* amcp = (u16*)&amc;
      #pragma unroll
      for (int e = 0; e < 8; ++e){
        const float ef = bf2f(arp[e]) * p;
        amep[e] = (u16)f2bf(ef);
        amcp[e] = (u16)f2bf(ef * bf2f(rvp[e]));
      }
      #pragma unroll
      for (int f = 0; f < 2; ++f){
        short8 bb = *(const short8*)&WgL[swze(chh*32 + f*16 + lr, k0)];
        eacc[f] = __builtin_amdgcn_mfma_f32_16x16x32_bf16(ame, bb, eacc[f], 0, 0, 0);
      }
      #pragma unroll
      for (int f = 0; f < 4; ++f){
        short8 bb = *(const short8*)&W1L[swze(chh*64 + f*16 + lr, k0)];
        cacc[f] = __builtin_amdgcn_mfma_f32_16x16x32_bf16(amc, bb, cacc[f], 0, 0, 0);
      }
    }
    #pragma unroll
    for (int f = 0; f < 2; ++f){
      const int g = chh*32 + f*16 + lr;
      #pragma unroll
      for (int r = 0; r < 4; ++r){
        const int j = j0 + jsb + kg*4 + r;
        edge_out[((size_t)bi*N_ + j)*64 + g] = eacc[f][r] + bgv[f];
      }
    }
    {
      float sr[4] = {0.f,0.f,0.f,0.f};
      #pragma unroll
      for (int f = 0; f < 4; ++f){
        #pragma unroll
        for (int r = 0; r < 4; ++r){
          float y = cacc[f][r] + bc1v[f]; y = y > 0.f ? y : 0.01f*y;
          sr[r] += y * w2v[f];
        }
      }
      #pragma unroll
      for (int r = 0; r < 4; ++r){
        float s = sr[r];
        s += __shfl_xor(s, 1); s += __shfl_xor(s, 2);
        s += __shfl_xor(s, 4); s += __shfl_xor(s, 8);
        if (lr == 0) catt[chh*N_ + j0 + jsb + kg*4 + r] = s;
      }
    }
  }
  __syncthreads();

  {
    float vx = 0.f, vy = 0.f, vz = 0.f, cnt = 0.f;
    if (t < N_){
      const int j = t;
      const int mk = emask[(size_t)bi*N_ + j];
      cnt = (mk != 0) ? 1.f : 0.f;
      if (mk){
        const float val = catt[j] + catt[N_ + j] + bc2[0];
        const float dx = cix - coor[(size_t)(b*N_+j)*3+0];
        const float dy = ciy - coor[(size_t)(b*N_+j)*3+1];
        const float dz = ciz - coor[(size_t)(b*N_+j)*3+2];
        const float nrm = sqrtf(dx*dx + dy*dy + dz*dz);
        if (nrm > 0.f){
          const float qq = val / fmaxf(nrm, 1e-8f);
          vx = qq*dx; vy = qq*dy; vz = qq*dz;
        }
      }
    }
    #pragma unroll
    for (int o = 32; o >= 1; o >>= 1){
      vx += __shfl_xor(vx, o); vy += __shfl_xor(vy, o);
      vz += __shfl_xor(vz, o); cnt += __shfl_xor(cnt, o);
    }
    if (l == 0){
      float* wr = misc + 16 + w*4;
      wr[0] = vx; wr[1] = vy; wr[2] = vz; wr[3] = cnt;
    }
  }
  __syncthreads();
  if (t == 0){
    float sx=0.f, sy=0.f, sz=0.f, sc=0.f;
    #pragma unroll
    for (int ww = 0; ww < 8; ++ww){
      sx += misc[16+ww*4]; sy += misc[16+ww*4+1];
      sz += misc[16+ww*4+2]; sc += misc[16+ww*4+3];
    }
    const float d = sc + 1e-7f, fm = (float)fmask[bi];
    coor_out[bi*3+0] = sx/d*fm; coor_out[bi*3+1] = sy/d*fm; coor_out[bi*3+2] = sz/d*fm;
  }

  {
    float* part = (float*)(smem + L_PART);
    const int c8 = t & 31, jg = t >> 5;
    const int ch0 = 256 + c8*8;
    const int h = (c8 < 16) ? (c8 >> 1) : ((c8 - 16) >> 1);
    const int slot0 = (c8 < 16) ? (h*32 + (c8 & 1)*8) : (h*32 + 16 + (c8 & 1)*8);
    float a8[8];
    #pragma unroll
    for (int e = 0; e < 8; ++e) a8[e] = 0.f;
    for (int q = 0; q < 24; ++q){
      const int j = jg*24 + q;
      const float p = att[j*8 + h];
      uint4 v = *(const uint4*)&qkbf[(size_t)(b*N_+j)*512 + ch0];
      const u16* vp = (const u16*)&v;
      #pragma unroll
      for (int e = 0; e < 8; ++e) a8[e] = fmaf(p, bf2f(vp[e]), a8[e]);
    }
    float4 o0 = {a8[0],a8[1],a8[2],a8[3]}, o1 = {a8[4],a8[5],a8[6],a8[7]};
    *(float4*)&part[jg*256 + slot0]     = o0;
    *(float4*)&part[jg*256 + slot0 + 4] = o1;
  }
  __syncthreads();
  {
    float* part = (float*)(smem + L_PART);
    float* red2 = (float*)(smem + L_RED2);
    if (t < 256){
      float s = 0.f;
      #pragma unroll
      for (int g = 0; g < 16; ++g) s += part[g*256 + t];
      red2[t] = s;
    }
  }
  __syncthreads();
  {
    float* part = (float*)(smem + L_PART);
    float* red2 = (float*)(smem + L_RED2);
    const int c = t & 127, qq = t >> 7;
    float s = 0.f;
    #pragma unroll 4
    for (int k = qq*64; k < qq*64 + 64; ++k)
      s = fmaf(red2[k], Wnode[(size_t)k*128 + c], s);
    part[qq*128 + c] = s;
    __syncthreads();
    if (t < 128)
      node_out[(size_t)bi*128 + t] = part[t] + part[128+t] + part[256+t] + part[384+t] + bnode[t];
  }
}

extern "C" void kernel_launch(void* const* d_in, const int* in_sizes, int n_in,
                              void* d_out, int out_size, void* d_ws, size_t ws_size,
                              hipStream_t stream)
{
  const float* x     = (const float*)d_in[0];
  const float* coor  = (const float*)d_in[1];
  const float* eattr = (const float*)d_in[2];
  const float* Wqk   = (const float*)d_in[3];
  const float* bqk   = (const float*)d_in[4];
  const float* We    = (const float*)d_in[5];
  const float* be    = (const float*)d_in[6];
  const float* Wnode = (const float*)d_in[7];
  const float* bnode = (const float*)d_in[8];
  const float* Wedge = (const float*)d_in[9];
  const float* bedge = (const float*)d_in[10];
  const float* Wc1   = (const float*)d_in[11];
  const float* bc1   = (const float*)d_in[12];
  const float* Wc2   = (const float*)d_in[13];
  const float* bc2   = (const float*)d_in[14];
  const int*   emask = (const int*)d_in[15];
  const int*   fmask = (const int*)d_in[16];

  u16* qkbf = (u16*)d_ws;                         // 786432 B

  float* out      = (float*)d_out;
  float* node_out = out;                           // 2*384*128
  float* edge_out = out + 98304;                   // 2*384*384*64
  float* coor_out = out + 98304 + 18874368;        // 2*384*3

  const size_t NEED     = 6799360;
  const size_t NEED_REP = 7716864;
  if (ws_size >= NEED){
    u16*   WeF   = (u16*)((char*)d_ws + 786432);   // 65536
    u16*   WgF   = (u16*)((char*)d_ws + 851968);   // 16384
    u16*   W1F   = (u16*)((char*)d_ws + 868352);   // 32768
    u16*   attL  = (u16*)((char*)d_ws + 901120);   // 4718592
    float* cattB = (float*)((char*)d_ws + 5619712);// 1179648
    u16*   WeR   = (u16*)((char*)d_ws + 6799360);  // 524288 (8 copies)
    u16*   WgR   = (u16*)((char*)d_ws + 7323648);  // 131072
    u16*   W1R   = (u16*)((char*)d_ws + 7454720);  // 262144

    const int rep = (ws_size >= NEED_REP);
    const u16* WeB = rep ? WeR : WeF;
    const u16* WgB = rep ? WgR : WgF;
    const u16* W1B = rep ? W1R : W1F;
    const int rmask = rep ? 7 : 0;

    prep_frag<<<dim3(28), dim3(256), 0, stream>>>(We, Wedge, Wc1, WeF, WgF, W1F);
    if (rep)
      prep_rep<<<dim3(224), dim3(256), 0, stream>>>(WeF, WgF, W1F,
          (uint4*)WeR, (uint4*)WgR, (uint4*)W1R);
    qk_kernel<<<dim3(192), dim3(256), 0, stream>>>(x, Wqk, bqk, qkbf);
    k1L_logits_ev<<<dim3(3, NB), dim3(256), 0, stream>>>(
        coor, eattr, be, emask, qkbf, WeB, rmask, attL, (u16*)edge_out);
    k2_softmax<<<dim3(NB), dim3(512), 0, stream>>>(attL);
    k3L_edge_c1<<<dim3(6, NB), dim3(256), 0, stream>>>(
        bedge, bc1, Wc2, qkbf, WgB, W1B, rmask, attL, edge_out, cattB);
    k4_node_coor<<<dim3(NB), dim3(256), 0, stream>>>(
        coor, Wnode, bnode, bc2, emask, fmask, qkbf, attL, cattB, node_out, coor_out);
  } else {
    u16* WeT  = (u16*)((char*)d_ws + 786432);
    u16* WgT  = (u16*)((char*)d_ws + 851968);
    u16* Wc1T = (u16*)((char*)d_ws + 868352);
    prep_wt<<<dim3(14), dim3(512), 0, stream>>>(We, Wedge, Wc1, WeT, WgT, Wc1T);
    qk_kernel<<<dim3(192), dim3(256), 0, stream>>>(x, Wqk, bqk, qkbf);
    se3_fused<<<dim3(NB), dim3(512), L_TOTAL, stream>>>(
        coor, eattr, be, bedge, Wnode, bnode, bc1, Wc2, bc2,
        emask, fmask, qkbf, WeT, WgT, Wc1T, node_out, edge_out, coor_out);
  }
}

// Round 15
// 175.297 us; speedup vs baseline: 1.0111x; 1.0111x over previous
//
#include <hip/hip_runtime.h>
#include <stdint.h>
#include <float.h>

#define N_   384
#define NB   768
typedef unsigned short u16;
typedef unsigned int   u32;
typedef __attribute__((ext_vector_type(8))) short short8;   // 8 bf16 (4 VGPRs)
typedef __attribute__((ext_vector_type(4))) float f32x4;    // MFMA accumulator

__device__ __forceinline__ u32 f2bf(float x){
  union{float f; u32 u;} v; v.f = x;
  return (v.u + 0x7fffu + ((v.u >> 16) & 1u)) >> 16;   // RNE bf16
}
__device__ __forceinline__ float bf2f(u16 s){
  union{u32 u; float f;} v; v.u = ((u32)s) << 16; return v.f;
}
__device__ __forceinline__ u32 packbf(float a, float b){
  return f2bf(a) | (f2bf(b) << 16);
}
__device__ __forceinline__ uint4 pack8(const float* f){
  uint4 u;
  u.x = packbf(f[0],f[1]); u.y = packbf(f[2],f[3]);
  u.z = packbf(f[4],f[5]); u.w = packbf(f[6],f[7]);
  return u;
}
__device__ __forceinline__ void unpack8(uint4 u, float* f){
  u32 w[4] = {u.x, u.y, u.z, u.w};
  #pragma unroll
  for (int q = 0; q < 4; ++q){
    union{u32 u; float f;} lo, hi;
    lo.u = w[q] << 16; hi.u = w[q] & 0xffff0000u;
    f[2*q] = lo.f; f[2*q+1] = hi.f;
  }
}
// element index into a [rows][128] bf16 tile, 16B-granule XOR swizzle
__device__ __forceinline__ int swze(int row, int k){
  return row*128 + (((k >> 3) ^ (row & 7)) << 3) + (k & 7);
}

// ---------------- qk = x @ W_qk + b_qk  (bf16 out) ----------------
__global__ __launch_bounds__(256) void qk_kernel(
    const float* __restrict__ x, const float* __restrict__ Wqk,
    const float* __restrict__ bqk, u16* __restrict__ qkbf)
{
  __shared__ float xs[4][128];
  const int r0 = blockIdx.x * 4;
  const int t = threadIdx.x;
  for (int idx = t; idx < 512; idx += 256){
    int r = idx >> 7, k = idx & 127;
    xs[r][k] = x[(size_t)(r0 + r)*128 + k];
  }
  __syncthreads();
  float acc[4][2];
  #pragma unroll
  for (int r = 0; r < 4; ++r){ acc[r][0] = bqk[t]; acc[r][1] = bqk[t + 256]; }
  #pragma unroll 4
  for (int k = 0; k < 128; ++k){
    float w0 = Wqk[(size_t)k*512 + t], w1 = Wqk[(size_t)k*512 + t + 256];
    #pragma unroll
    for (int r = 0; r < 4; ++r){
      acc[r][0] = fmaf(xs[r][k], w0, acc[r][0]);
      acc[r][1] = fmaf(xs[r][k], w1, acc[r][1]);
    }
  }
  #pragma unroll
  for (int r = 0; r < 4; ++r){
    qkbf[(size_t)(r0+r)*512 + t]       = (u16)f2bf(acc[r][0]);
    qkbf[(size_t)(r0+r)*512 + t + 256] = (u16)f2bf(acc[r][1]);
  }
}

// =====================================================================
// ===================== PRIMARY (split) PATH ==========================
// =====================================================================

// fragment-major weight pack: frag (fc,ks): lane l holds W[k=ks*32+(l>>4)*8+e][c=fc*16+(l&15)]
__global__ __launch_bounds__(256) void prep_frag(
    const float* __restrict__ We, const float* __restrict__ Wedge,
    const float* __restrict__ Wc1, u16* __restrict__ WeF,
    u16* __restrict__ WgF, u16* __restrict__ W1F)
{
  const int id = blockIdx.x*256 + threadIdx.x;   // 28 blocks * 256 = 7168 = 112 frags * 64
  const int frag = id >> 6, lane = id & 63;
  if (frag >= 112) return;
  const float* src; u16* dst; int C, fc, ks;
  if (frag < 64){       fc = frag >> 2;      ks = frag & 3; src = We;    C = 256; dst = WeF + (size_t)frag*512; }
  else if (frag < 80){  int fr = frag - 64; fc = fr >> 2;   ks = fr & 3; src = Wedge; C = 64;  dst = WgF + (size_t)fr*512; }
  else {                int fr = frag - 80; fc = fr >> 2;   ks = fr & 3; src = Wc1;   C = 128; dst = W1F + (size_t)fr*512; }
  const int c = fc*16 + (lane & 15);
  const int kb = ks*32 + (lane >> 4)*8;
  float f[8];
  #pragma unroll
  for (int e = 0; e < 8; ++e) f[e] = src[(size_t)(kb + e)*C + c];
  *(uint4*)(dst + lane*8) = pack8(f);
}

// ---------------- K1L: dual-tile swapped e-GEMM, weights in LDS ----------------
// Best-known structure (R13): 64KB WeF in LDS, dual 16-j tiles per wave,
// epilogue gathers hoisted to entry, e_v written direct to parked image.
__global__ __launch_bounds__(256, 2) void k1L_logits_ev(
    const float* __restrict__ coor, const float* __restrict__ edge_attr,
    const float* __restrict__ be, const int* __restrict__ emask,
    const u16* __restrict__ qkbf, const u16* __restrict__ WeF,
    u16* __restrict__ attL, u16* __restrict__ evG)
{
  __shared__ u16 WeL[32768];   // 64 KB: 64 frags x 512 u16
  const int t = threadIdx.x;
  const int ch = blockIdx.x, bi = blockIdx.y;     // ch: 0..2 (128-j blocks)
  const int b = (bi >= N_) ? 1 : 0;
  const int w = t >> 6, l = t & 63, lr = l & 15, kg = l >> 4;
  const int jw = ch*128 + w*32;
  const int ja0 = jw + lr, ja1 = jw + 16 + lr;

  // ---- HOISTED epilogue gathers: in flight under staging + MFMA ----
  const int mk0 = emask[(size_t)bi*N_ + ja0];
  const int mk1 = emask[(size_t)bi*N_ + ja1];
  uint2 rmu0[8], rmu1[8], lmu[8];
  float4 bevA[8];
  #pragma unroll
  for (int mf = 0; mf < 8; ++mf){
    const int c = mf*16 + kg*4;
    lmu[mf]  = *(const uint2*)&qkbf[(size_t)bi*512 + c];
    rmu0[mf] = *(const uint2*)&qkbf[(size_t)(b*N_+ja0)*512 + 128 + c];
    rmu1[mf] = *(const uint2*)&qkbf[(size_t)(b*N_+ja1)*512 + 128 + c];
    bevA[mf] = *(const float4*)&be[c];
  }

  // ---- edge fragments for both tiles (lane: 16-idx = j, k = kg*8+e) ----
  short8 afr0[4], afr1[4];
  {
    const float cix = coor[bi*3], ciy = coor[bi*3+1], ciz = coor[bi*3+2];
    const float* s0 = &edge_attr[((size_t)bi*N_ + ja0)*64 + kg*8];
    const float* s1 = &edge_attr[((size_t)bi*N_ + ja1)*64 + kg*8];
    #pragma unroll
    for (int ks = 0; ks < 2; ++ks){
      float4 a  = *(const float4*)(s0 + ks*32);
      float4 c4 = *(const float4*)(s0 + ks*32 + 4);
      float f[8] = {a.x,a.y,a.z,a.w,c4.x,c4.y,c4.z,c4.w};
      *(uint4*)&afr0[ks] = pack8(f);
      a  = *(const float4*)(s1 + ks*32);
      c4 = *(const float4*)(s1 + ks*32 + 4);
      float g[8] = {a.x,a.y,a.z,a.w,c4.x,c4.y,c4.z,c4.w};
      *(uint4*)&afr1[ks] = pack8(g);
    }
    float dx = cix - coor[(size_t)(b*N_+ja0)*3+0];
    float dy = ciy - coor[(size_t)(b*N_+ja0)*3+1];
    float dz = ciz - coor[(size_t)(b*N_+ja0)*3+2];
    const float dm0 = fminf(sqrtf(dx*dx + dy*dy + dz*dz), 2.0f);
    dx = cix - coor[(size_t)(b*N_+ja1)*3+0];
    dy = ciy - coor[(size_t)(b*N_+ja1)*3+1];
    dz = ciz - coor[(size_t)(b*N_+ja1)*3+2];
    const float dm1 = fminf(sqrtf(dx*dx + dy*dy + dz*dz), 2.0f);
    #pragma unroll
    for (int ks = 2; ks < 4; ++ks){
      const int g0 = (ks-2)*32 + kg*8;
      float f[8], g[8];
      #pragma unroll
      for (int e = 0; e < 8; ++e){
        const float x0 = (float)(g0+e)*(2.0f/63.0f);
        const float d0 = dm0 - x0, d1 = dm1 - x0;
        f[e] = __expf(-496.125f * d0 * d0);   // coeff = -0.5/(2/63)^2
        g[e] = __expf(-496.125f * d1 * d1);
      }
      *(uint4*)&afr0[ks] = pack8(f);
      *(uint4*)&afr1[ks] = pack8(g);
    }
  }

  // ---- stage WeF into LDS (64 KB, coalesced) ----
  for (int idx = t; idx < 4096; idx += 256)
    ((uint4*)WeL)[idx] = ((const uint4*)WeF)[idx];
  __syncthreads();

  // ---- group A: e_m channels (fc 0..7) -> logits for both tiles ----
  f32x4 a0[8], a1[8];
  #pragma unroll
  for (int f = 0; f < 8; ++f){ a0[f] = (f32x4){0.f,0.f,0.f,0.f}; a1[f] = (f32x4){0.f,0.f,0.f,0.f}; }
  #pragma unroll
  for (int ks = 0; ks < 4; ++ks){
    #pragma unroll
    for (int mf = 0; mf < 8; ++mf){
      short8 wv = *(const short8*)&WeL[((mf*4 + ks)*64 + l)*8];
      a0[mf] = __builtin_amdgcn_mfma_f32_16x16x32_bf16(wv, afr0[ks], a0[mf], 0, 0, 0);
      a1[mf] = __builtin_amdgcn_mfma_f32_16x16x32_bf16(wv, afr1[ks], a1[mf], 0, 0, 0);
    }
  }
  #pragma unroll
  for (int tile = 0; tile < 2; ++tile){
    const int ja = tile ? ja1 : ja0;
    const f32x4* ac = tile ? a1 : a0;
    const int mk = tile ? mk1 : mk0;
    float s8[8];
    #pragma unroll
    for (int mf = 0; mf < 8; ++mf){
      const uint2 rmuv = tile ? rmu1[mf] : rmu0[mf];
      const u16* lmp = (const u16*)&lmu[mf];
      const u16* rmp = (const u16*)&rmuv;
      float s = 0.f;
      #pragma unroll
      for (int r = 0; r < 4; ++r){
        float e = ac[mf][r] + (&bevA[mf].x)[r]; e = e > 0.f ? e : 0.01f*e;
        s += e * bf2f(lmp[r]) * bf2f(rmp[r]);
      }
      s += __shfl_xor(s, 16); s += __shfl_xor(s, 32);
      s8[mf] = s * 0.25f;
    }
    if (kg == 0){
      const u32 NEG2 = packbf(-1e30f, -1e30f);
      uint4 o;
      o.x = mk ? packbf(s8[0], s8[1]) : NEG2;
      o.y = mk ? packbf(s8[2], s8[3]) : NEG2;
      o.z = mk ? packbf(s8[4], s8[5]) : NEG2;
      o.w = mk ? packbf(s8[6], s8[7]) : NEG2;
      *(uint4*)&attL[(size_t)bi*3072 + ja*8] = o;
    }
  }

  // ---- group B: e_v channels (fc 8..15) -> DIRECT swizzled global stores ----
  #pragma unroll
  for (int f = 0; f < 8; ++f){ a0[f] = (f32x4){0.f,0.f,0.f,0.f}; a1[f] = (f32x4){0.f,0.f,0.f,0.f}; }
  #pragma unroll
  for (int ks = 0; ks < 4; ++ks){
    #pragma unroll
    for (int mf = 0; mf < 8; ++mf){
      short8 wv = *(const short8*)&WeL[(((8+mf)*4 + ks)*64 + l)*8];
      a0[mf] = __builtin_amdgcn_mfma_f32_16x16x32_bf16(wv, afr0[ks], a0[mf], 0, 0, 0);
      a1[mf] = __builtin_amdgcn_mfma_f32_16x16x32_bf16(wv, afr1[ks], a1[mf], 0, 0, 0);
    }
  }
  #pragma unroll
  for (int tile = 0; tile < 2; ++tile){
    const f32x4* ac = tile ? a1 : a0;
    const int jl = w*32 + tile*16 + lr;          // 0..127 within block
    const int chunk = ch*2 + (jl >> 6);          // 64-j chunk index
    const int row = jl & 63;
    u16* dstb = evG + ((size_t)bi*6 + chunk)*8192 + row*128;
    #pragma unroll
    for (int mf = 0; mf < 8; ++mf){
      const int c = mf*16 + kg*4;                // c within [0,128) of the e_v half
      float4 bev = *(const float4*)&be[128 + c];
      float e[4];
      #pragma unroll
      for (int r = 0; r < 4; ++r){
        float y = ac[mf][r] + (&bev.x)[r]; e[r] = y > 0.f ? y : 0.01f*y;
      }
      uint2 pk; pk.x = packbf(e[0], e[1]); pk.y = packbf(e[2], e[3]);
      const int g = c >> 3;
      *(uint2*)&dstb[((g ^ (row & 7)) << 3) + (kg & 1)*4] = pk;
    }
  }
}

// ---------------- K2: softmax over j, probs bf16 in place ----------------
__global__ __launch_bounds__(512) void k2_softmax(u16* __restrict__ attL)
{
  __shared__ u16 sl[3072];
  const int t = threadIdx.x, bi = blockIdx.x;
  uint4* sl4 = (uint4*)sl;
  if (t < 384) sl4[t] = ((const uint4*)(attL + (size_t)bi*3072))[t];
  __syncthreads();
  const int h = t >> 6, lane = t & 63;
  float v[6]; float m = -FLT_MAX;
  #pragma unroll
  for (int q = 0; q < 6; ++q){ v[q] = bf2f(sl[(lane + q*64)*8 + h]); m = fmaxf(m, v[q]); }
  #pragma unroll
  for (int o = 32; o >= 1; o >>= 1) m = fmaxf(m, __shfl_xor(m, o));
  float s = 0.f;
  #pragma unroll
  for (int q = 0; q < 6; ++q){ v[q] = __expf(v[q] - m); s += v[q]; }
  #pragma unroll
  for (int o = 32; o >= 1; o >>= 1) s += __shfl_xor(s, o);
  const float inv = 1.f / s;
  #pragma unroll
  for (int q = 0; q < 6; ++q) sl[(lane + q*64)*8 + h] = (u16)f2bf(v[q] * inv);
  __syncthreads();
  if (t < 384) ((uint4*)(attL + (size_t)bi*3072))[t] = sl4[t];
}

// ---------------- K3L: swapped edge+c1 GEMM, weights in LDS ----------------
__global__ __launch_bounds__(256, 3) void k3L_edge_c1(
    const float* __restrict__ bedge, const float* __restrict__ bc1,
    const float* __restrict__ Wc2, const u16* __restrict__ qkbf,
    const u16* __restrict__ WgF, const u16* __restrict__ W1F,
    const u16* __restrict__ attL, float* __restrict__ edge_out,
    float* __restrict__ cattB)
{
  __shared__ u16 WL[24576];   // 48 KB: Wg 16 frags (8192 u16) + W1 32 frags (16384 u16)
  const int t = threadIdx.x, ch = blockIdx.x, bi = blockIdx.y;
  const int b = (bi >= N_) ? 1 : 0;
  const int j0 = ch * 64;
  const int w = t >> 6, l = t & 63, lr = l & 15, kg = l >> 4;
  const int jloc = w*16 + lr;
  const int jglob = j0 + jloc;
  const u16* evS = (const u16*)edge_out + ((size_t)bi*6 + ch)*8192;

  for (int idx = t; idx < 3072; idx += 256)
    ((uint4*)WL)[idx] = (idx < 1024) ? ((const uint4*)WgF)[idx]
                                     : ((const uint4*)W1F)[idx - 1024];
  __syncthreads();
  const u16* WgL = WL;
  const u16* W1L = WL + 8192;

  f32x4 eacc[4], cacc[8];
  #pragma unroll
  for (int f = 0; f < 4; ++f) eacc[f] = (f32x4){0.f,0.f,0.f,0.f};
  #pragma unroll
  for (int f = 0; f < 8; ++f) cacc[f] = (f32x4){0.f,0.f,0.f,0.f};

  #pragma unroll
  for (int ks = 0; ks < 4; ++ks){
    const int k0 = ks*32 + kg*8;
    short8 ar = *(const short8*)&evS[swze(jloc, k0)];
    const float p = bf2f(attL[(size_t)bi*3072 + jglob*8 + (k0 >> 4)]);
    uint4 rvu = *(const uint4*)&qkbf[(size_t)(b*N_ + jglob)*512 + 384 + k0];
    uint4 lvu = *(const uint4*)&qkbf[(size_t)bi*512 + 256 + k0];
    short8 ame, amc;
    const u16* arp = (const u16*)&ar;
    const u16* rvp = (const u16*)&rvu;
    const u16* lvp = (const u16*)&lvu;
    u16* amep = (u16*)&ame; u16* amcp = (u16*)&amc;
    #pragma unroll
    for (int e = 0; e < 8; ++e){
      const float ef = bf2f(arp[e]) * p;
      amep[e] = (u16)f2bf(ef);
      amcp[e] = (u16)f2bf(ef * bf2f(lvp[e]) * bf2f(rvp[e]));
    }
    #pragma unroll
    for (int f = 0; f < 4; ++f){
      short8 wv = *(const short8*)&WgL[((f*4 + ks)*64 + l)*8];
      eacc[f] = __builtin_amdgcn_mfma_f32_16x16x32_bf16(wv, ame, eacc[f], 0, 0, 0);
    }
    #pragma unroll
    for (int f = 0; f < 8; ++f){
      short8 wv = *(const short8*)&W1L[((f*4 + ks)*64 + l)*8];
      cacc[f] = __builtin_amdgcn_mfma_f32_16x16x32_bf16(wv, amc, cacc[f], 0, 0, 0);
    }
  }
  // edge epilogue: D[g, j] -> lane j fixed, g = gf*16 + kg*4 + r -> float4 stores
  #pragma unroll
  for (int gf = 0; gf < 4; ++gf){
    const int g0 = gf*16 + kg*4;
    float4 bg = *(const float4*)&bedge[g0];
    float4 o;
    o.x = eacc[gf][0] + bg.x; o.y = eacc[gf][1] + bg.y;
    o.z = eacc[gf][2] + bg.z; o.w = eacc[gf][3] + bg.w;
    *(float4*)&edge_out[((size_t)bi*N_ + jglob)*64 + g0] = o;
  }
  // c1 epilogue: lane-local 32 terms + 2 shfl
  {
    float s = 0.f;
    #pragma unroll
    for (int cf = 0; cf < 8; ++cf){
      const int c0 = cf*16 + kg*4;
      float4 b1 = *(const float4*)&bc1[c0];
      float4 w2 = *(const float4*)&Wc2[c0];
      #pragma unroll
      for (int r = 0; r < 4; ++r){
        float y = cacc[cf][r] + (&b1.x)[r]; y = y > 0.f ? y : 0.01f*y;
        s += y * (&w2.x)[r];
      }
    }
    s += __shfl_xor(s, 16); s += __shfl_xor(s, 32);
    if (kg == 0) cattB[(size_t)bi*N_ + jglob] = s;
  }
}

// ---------------- K4: node einsum (vectorized) + W_node + coor finale ----------------
__global__ __launch_bounds__(256) void k4_node_coor(
    const float* __restrict__ coor, const float* __restrict__ Wnode,
    const float* __restrict__ bnode, const float* __restrict__ bc2,
    const int* __restrict__ emask, const int* __restrict__ fmask,
    const u16* __restrict__ qkbf, const u16* __restrict__ attL,
    const float* __restrict__ cattB, float* __restrict__ node_out,
    float* __restrict__ coor_out)
{
  __shared__ u16 pS[3072];
  __shared__ float part[8][256];
  __shared__ float red[256];
  __shared__ float halfb[256];
  __shared__ float cred[16];
  const int t = threadIdx.x, bi = blockIdx.x;
  const int b = (bi >= N_) ? 1 : 0;
  for (int idx = t; idx < 384; idx += 256)
    ((uint4*)pS)[idx] = ((const uint4*)(attL + (size_t)bi*3072))[idx];
  __syncthreads();
  // node pre: 32 chan-groups (uint4) x 8 j-groups of 48 j
  {
    const int q = t & 31, jg = t >> 5;
    const int ch0 = 256 + q*8;
    const int h = (q < 16) ? (q >> 1) : ((q - 16) >> 1);
    const int slot0 = (q < 16) ? (h*32 + (q & 1)*8) : (h*32 + 16 + (q & 1)*8);
    float a8[8];
    #pragma unroll
    for (int e = 0; e < 8; ++e) a8[e] = 0.f;
    for (int j = jg*48; j < jg*48 + 48; ++j){
      const float p = bf2f(pS[j*8 + h]);
      uint4 v = *(const uint4*)&qkbf[(size_t)(b*N_+j)*512 + ch0];
      const u16* vp = (const u16*)&v;
      #pragma unroll
      for (int e = 0; e < 8; ++e) a8[e] = fmaf(p, bf2f(vp[e]), a8[e]);
    }
    float4 o0 = {a8[0],a8[1],a8[2],a8[3]}, o1 = {a8[4],a8[5],a8[6],a8[7]};
    *(float4*)&part[jg][slot0]     = o0;
    *(float4*)&part[jg][slot0 + 4] = o1;
  }
  __syncthreads();
  {
    float s = 0.f;
    #pragma unroll
    for (int g = 0; g < 8; ++g) s += part[g][t];
    red[t] = s;
  }
  __syncthreads();
  {
    const int c = t & 127, qq = t >> 7;
    float s = 0.f;
    #pragma unroll 4
    for (int k = qq*128; k < qq*128 + 128; ++k)
      s = fmaf(red[k], Wnode[(size_t)k*128 + c], s);
    halfb[t] = s;
  }
  __syncthreads();
  if (t < 128)
    node_out[(size_t)bi*128 + t] = halfb[t] + halfb[128 + t] + bnode[t];

  // coor
  {
    const float cix = coor[bi*3], ciy = coor[bi*3+1], ciz = coor[bi*3+2];
    float vx=0.f, vy=0.f, vz=0.f, cnt=0.f;
    for (int j = t; j < N_; j += 256){
      if (emask[(size_t)bi*N_ + j]){
        cnt += 1.f;
        const float val = cattB[(size_t)bi*N_ + j] + bc2[0];
        const float dx = cix - coor[(size_t)(b*N_+j)*3+0];
        const float dy = ciy - coor[(size_t)(b*N_+j)*3+1];
        const float dz = ciz - coor[(size_t)(b*N_+j)*3+2];
        const float nrm = sqrtf(dx*dx + dy*dy + dz*dz);
        if (nrm > 0.f){
          const float qv = val / fmaxf(nrm, 1e-8f);
          vx += qv*dx; vy += qv*dy; vz += qv*dz;
        }
      }
    }
    #pragma unroll
    for (int o = 32; o >= 1; o >>= 1){
      vx += __shfl_xor(vx, o); vy += __shfl_xor(vy, o);
      vz += __shfl_xor(vz, o); cnt += __shfl_xor(cnt, o);
    }
    const int w = t >> 6, l = t & 63;
    if (l == 0){ cred[w*4]=vx; cred[w*4+1]=vy; cred[w*4+2]=vz; cred[w*4+3]=cnt; }
  }
  __syncthreads();
  if (t == 0){
    float sx=0.f, sy=0.f, sz=0.f, sc=0.f;
    #pragma unroll
    for (int ww = 0; ww < 4; ++ww){
      sx += cred[ww*4]; sy += cred[ww*4+1]; sz += cred[ww*4+2]; sc += cred[ww*4+3];
    }
    const float d = sc + 1e-7f, fm = (float)fmask[bi];
    coor_out[bi*3+0] = sx/d*fm;
    coor_out[bi*3+1] = sy/d*fm;
    coor_out[bi*3+2] = sz/d*fm;
  }
}

// =====================================================================
// ================= FALLBACK (R3 monolithic) PATH =====================
// =====================================================================

__global__ __launch_bounds__(512) void prep_wt(
    const float* __restrict__ We, const float* __restrict__ Wedge,
    const float* __restrict__ Wc1, u16* __restrict__ WeT,
    u16* __restrict__ WgT, u16* __restrict__ Wc1T)
{
  const int id = blockIdx.x*512 + threadIdx.x;
  const float* src; u16* dst; int c, g, stride;
  if (id < 4096){        int q = id;      c = q>>4; g = q&15; src = We    + (size_t)g*8*256 + c; stride = 256; dst = WeT  + c*128 + ((g ^ (c&7))<<3); }
  else if (id < 5120){   int q = id-4096; c = q>>4; g = q&15; src = Wedge + (size_t)g*8*64  + c; stride = 64;  dst = WgT  + c*128 + ((g ^ (c&7))<<3); }
  else if (id < 7168){   int q = id-5120; c = q>>4; g = q&15; src = Wc1   + (size_t)g*8*128 + c; stride = 128; dst = Wc1T + c*128 + ((g ^ (c&7))<<3); }
  else return;
  float f[8];
  #pragma unroll
  for (int e = 0; e < 8; ++e) f[e] = src[(size_t)e*stride];
  *(uint4*)dst = pack8(f);
}

#define L_ATT   0
#define L_AS    12288
#define L_WE    45056
#define L_WG    45056
#define L_W1    61440
#define L_PART  94208
#define L_EVP   110592
#define L_CATT  110592
#define L_RED2  113664
#define L_MISC  126976
#define L_QIF   127488
#define L_TOTAL 129536

__global__ __launch_bounds__(512, 1) void se3_fused(
    const float* __restrict__ coor, const float* __restrict__ edge_attr,
    const float* __restrict__ be, const float* __restrict__ bedge,
    const float* __restrict__ Wnode, const float* __restrict__ bnode,
    const float* __restrict__ bc1, const float* __restrict__ Wc2,
    const float* __restrict__ bc2, const int* __restrict__ emask,
    const int* __restrict__ fmask, const u16* __restrict__ qkbf,
    const u16* __restrict__ WeTg, const u16* __restrict__ WgTg,
    const u16* __restrict__ Wc1Tg,
    float* __restrict__ node_out, float* __restrict__ edge_out, float* __restrict__ coor_out)
{
  extern __shared__ char smem[];
  float* att  = (float*)(smem + L_ATT);
  float* qif  = (float*)(smem + L_QIF);
  float* misc = (float*)(smem + L_MISC);

  const int t  = threadIdx.x;
  const int bi = blockIdx.x;
  const int b  = (bi >= N_) ? 1 : 0;
  const float cix = coor[bi*3], ciy = coor[bi*3+1], ciz = coor[bi*3+2];

  const int w  = t >> 6, l = t & 63;
  const int chh = w >> 2, jsb = (w & 3) * 16;
  const int lr = l & 15, kg = l >> 4;

  for (int idx = t; idx < 4096; idx += 512)
    ((uint4*)(smem + L_WE))[idx] = ((const uint4*)WeTg)[idx];
  qif[t] = bf2f(qkbf[(size_t)bi*512 + t]);
  __syncthreads();

  float bevf[8], lmvf[8];
  #pragma unroll
  for (int f = 0; f < 8; ++f){
    const int c = chh*128 + f*16 + lr;
    bevf[f] = be[c];
    lmvf[f] = (chh == 0) ? qif[c] : 0.f;
  }

  float4 pa0, pb0, pa1, pb1;
  const int gq = t & 15, rq = t >> 4;
  auto issue_ea = [&](int j0){
    if (gq < 8){
      const float* s0 = &edge_attr[((size_t)bi*N_ + j0 + rq)*64 + gq*8];
      const float* s1 = &edge_attr[((size_t)bi*N_ + j0 + rq + 32)*64 + gq*8];
      pa0 = *(const float4*)s0; pb0 = *(const float4*)(s0 + 4);
      pa1 = *(const float4*)s1; pb1 = *(const float4*)(s1 + 4);
    }
  };

  uint4* evg = (uint4*)(edge_out + (size_t)bi*24576);

  issue_ea(0);
  for (int ch = 0; ch < 6; ++ch){
    const int j0 = ch * 64;
    {
      u16* As = (u16*)(smem + L_AS + (ch & 1)*16384);
      #pragma unroll
      for (int q = 0; q < 2; ++q){
        const int row = rq + q*32;
        const int j = j0 + row;
        float f[8];
        if (gq < 8){
          float4 A = q ? pa1 : pa0, Bv = q ? pb1 : pb0;
          f[0]=A.x; f[1]=A.y; f[2]=A.z; f[3]=A.w;
          f[4]=Bv.x; f[5]=Bv.y; f[6]=Bv.z; f[7]=Bv.w;
        } else {
          const float dx = cix - coor[(size_t)(b*N_+j)*3+0];
          const float dy = ciy - coor[(size_t)(b*N_+j)*3+1];
          const float dz = ciz - coor[(size_t)(b*N_+j)*3+2];
          const float dm = fminf(sqrtf(dx*dx + dy*dy + dz*dz), 2.0f);
          const int k0 = (gq - 8)*8;
          #pragma unroll
          for (int e = 0; e < 8; ++e){
            const float dd = dm - (float)(k0+e)*(2.0f/63.0f);
            f[e] = __expf(-496.125f * dd * dd);
          }
        }
        ((uint4*)As)[row*16 + (gq ^ (row & 7))] = pack8(f);
      }
    }
    __syncthreads();
    if (ch + 1 < 6) issue_ea((ch+1)*64);

    f32x4 acc[8];
    #pragma unroll
    for (int f = 0; f < 8; ++f) acc[f] = (f32x4){0.f,0.f,0.f,0.f};
    {
      u16* As  = (u16*)(smem + L_AS + (ch & 1)*16384);
      u16* WeL = (u16*)(smem + L_WE);
      #pragma unroll
      for (int ks = 0; ks < 4; ++ks){
        const int k0 = ks*32 + kg*8;
        short8 a = *(const short8*)&As[swze(jsb + lr, k0)];
        #pragma unroll
        for (int f = 0; f < 8; ++f){
          const int c = chh*128 + f*16 + lr;
          short8 bb = *(const short8*)&WeL[swze(c, k0)];
          acc[f] = __builtin_amdgcn_mfma_f32_16x16x32_bf16(a, bb, acc[f], 0, 0, 0);
        }
      }
    }
    if (chh == 0){
      #pragma unroll
      for (int f = 0; f < 8; ++f){
        #pragma unroll
        for (int r = 0; r < 4; ++r){
          const int j = j0 + jsb + kg*4 + r;
          float e = acc[f][r] + bevf[f]; e = e > 0.f ? e : 0.01f*e;
          const float rm = bf2f(qkbf[(size_t)(b*N_+j)*512 + 128 + f*16 + lr]);
          float s = lmvf[f] * rm * e;
          s += __shfl_xor(s, 1); s += __shfl_xor(s, 2);
          s += __shfl_xor(s, 4); s += __shfl_xor(s, 8);
          if (lr == 0)
            att[j*8 + f] = emask[(size_t)bi*N_ + j] ? s*0.25f : -FLT_MAX;
        }
      }
    } else {
      u16* Evp = (u16*)(smem + L_EVP);
      #pragma unroll
      for (int f = 0; f < 8; ++f){
        #pragma unroll
        for (int r = 0; r < 4; ++r){
          float e = acc[f][r] + bevf[f]; e = e > 0.f ? e : 0.01f*e;
          const float pr = __shfl_xor(e, 1);
          if (!(lr & 1)){
            const int jl = jsb + kg*4 + r;
            const int cv = f*16 + lr;
            *(u32*)&Evp[jl*128 + (((cv>>3) ^ (jl&7))<<3) + (cv&7)] = packbf(e, pr);
          }
        }
      }
    }
    __syncthreads();
    {
      const uint4* Evp4 = (const uint4*)(smem + L_EVP);
      #pragma unroll
      for (int q = 0; q < 2; ++q)
        evg[ch*1024 + t + q*512] = Evp4[t + q*512];
    }
  }

  {
    const int h = w, lane = l;
    float m = -FLT_MAX;
    #pragma unroll
    for (int q = 0; q < 6; ++q) m = fmaxf(m, att[(lane + q*64)*8 + h]);
    #pragma unroll
    for (int o = 32; o >= 1; o >>= 1) m = fmaxf(m, __shfl_xor(m, o));
    float pv[6], s = 0.f;
    #pragma unroll
    for (int q = 0; q < 6; ++q){ float p = __expf(att[(lane + q*64)*8 + h] - m); pv[q] = p; s += p; }
    #pragma unroll
    for (int o = 32; o >= 1; o >>= 1) s += __shfl_xor(s, o);
    const float inv = 1.f / s;
    #pragma unroll
    for (int q = 0; q < 6; ++q) att[(lane + q*64)*8 + h] = pv[q] * inv;
  }

  for (int idx = t; idx < 1024; idx += 512)
    ((uint4*)(smem + L_WG))[idx] = ((const uint4*)WgTg)[idx];
  for (int idx = t; idx < 2048; idx += 512){
    const int c = idx >> 4, g = idx & 15;
    uint4 u = ((const uint4*)Wc1Tg)[idx];
    const int k0 = ((g ^ (c & 7)) << 3);
    float f[8]; unpack8(u, f);
    #pragma unroll
    for (int e = 0; e < 8; ++e) f[e] *= qif[256 + k0 + e];
    ((uint4*)(smem + L_W1))[idx] = pack8(f);
  }

  float bgv[2], bc1v[4], w2v[4];
  #pragma unroll
  for (int f = 0; f < 2; ++f) bgv[f] = bedge[chh*32 + f*16 + lr];
  #pragma unroll
  for (int f = 0; f < 4; ++f){
    const int c2 = chh*64 + f*16 + lr;
    bc1v[f] = bc1[c2]; w2v[f] = Wc2[c2];
  }

  uint4 eva, evb;
  auto issue_ev = [&](int ch){
    eva = evg[ch*1024 + t];
    evb = evg[ch*1024 + t + 512];
  };
  issue_ev(0);
  __syncthreads();

  float* catt = (float*)(smem + L_CATT);

  for (int ch = 0; ch < 6; ++ch){
    const int j0 = ch * 64;
    {
      uint4* Ev4 = (uint4*)(smem + L_AS + (ch & 1)*16384);
      Ev4[t] = eva; Ev4[t + 512] = evb;
    }
    if (ch + 1 < 6) issue_ev(ch + 1);
    __syncthreads();

    u16* Ev  = (u16*)(smem + L_AS + (ch & 1)*16384);
    u16* WgL = (u16*)(smem + L_WG);
    u16* W1L = (u16*)(smem + L_W1);
    const int jrow = j0 + jsb + lr;

    f32x4 eacc[2], cacc[4];
    eacc[0] = (f32x4){0.f,0.f,0.f,0.f}; eacc[1] = (f32x4){0.f,0.f,0.f,0.f};
    #pragma unroll
    for (int f = 0; f < 4; ++f) cacc[f] = (f32x4){0.f,0.f,0.f,0.f};

    #pragma unroll
    for (int ks = 0; ks < 4; ++ks){
      const int k0 = ks*32 + kg*8;
      short8 ar = *(const short8*)&Ev[swze(jsb + lr, k0)];
      const float p = att[jrow*8 + (k0 >> 4)];
      uint4 rvu = *(const uint4*)&qkbf[(size_t)(b*N_+jrow)*512 + 384 + k0];
      short8 ame, amc;
      const u16* arp = (const u16*)&ar; const u16* rvp = (const u16*)&rvu;
      u16* amep = (u16*)&ame; u16* amcp = (u16*)&amc;
      #pragma unroll
      for (int e = 0; e < 8; ++e){
        const float ef = bf2f(arp[e]) * p;
        amep[e] = (u16)f2bf(ef);
        amcp[e] = (u16)f2bf(ef * bf2f(rvp[e]));
      }
      #pragma unroll
      for (int f = 0; f < 2; ++f){
        short8 bb = *(const short8*)&WgL[swze(chh*32 + f*16 + lr, k0)];
        eacc[f] = __builtin_amdgcn_mfma_f32_16x16x32_bf16(ame, bb, eacc[f], 0, 0, 0);
      }
      #pragma unroll
      for (int f = 0; f < 4; ++f){
        short8 bb = *(const short8*)&W1L[swze(chh*64 + f*16 + lr, k0)];
        cacc[f] = __builtin_amdgcn_mfma_f32_16x16x32_bf16(amc, bb, cacc[f], 0, 0, 0);
      }
    }
    #pragma unroll
    for (int f = 0; f < 2; ++f){
      const int g = chh*32 + f*16 + lr;
      #pragma unroll
      for (int r = 0; r < 4; ++r){
        const int j = j0 + jsb + kg*4 + r;
        edge_out[((size_t)bi*N_ + j)*64 + g] = eacc[f][r] + bgv[f];
      }
    }
    {
      float sr[4] = {0.f,0.f,0.f,0.f};
      #pragma unroll
      for (int f = 0; f < 4; ++f){
        #pragma unroll
        for (int r = 0; r < 4; ++r){
          float y = cacc[f][r] + bc1v[f]; y = y > 0.f ? y : 0.01f*y;
          sr[r] += y * w2v[f];
        }
      }
      #pragma unroll
      for (int r = 0; r < 4; ++r){
        float s = sr[r];
        s += __shfl_xor(s, 1); s += __shfl_xor(s, 2);
        s += __shfl_xor(s, 4); s += __shfl_xor(s, 8);
        if (lr == 0) catt[chh*N_ + j0 + jsb + kg*4 + r] = s;
      }
    }
  }
  __syncthreads();

  {
    float vx = 0.f, vy = 0.f, vz = 0.f, cnt = 0.f;
    if (t < N_){
      const int j = t;
      const int mk = emask[(size_t)bi*N_ + j];
      cnt = (mk != 0) ? 1.f : 0.f;
      if (mk){
        const float val = catt[j] + catt[N_ + j] + bc2[0];
        const float dx = cix - coor[(size_t)(b*N_+j)*3+0];
        const float dy = ciy - coor[(size_t)(b*N_+j)*3+1];
        const float dz = ciz - coor[(size_t)(b*N_+j)*3+2];
        const float nrm = sqrtf(dx*dx + dy*dy + dz*dz);
        if (nrm > 0.f){
          const float qq = val / fmaxf(nrm, 1e-8f);
          vx = qq*dx; vy = qq*dy; vz = qq*dz;
        }
      }
    }
    #pragma unroll
    for (int o = 32; o >= 1; o >>= 1){
      vx += __shfl_xor(vx, o); vy += __shfl_xor(vy, o);
      vz += __shfl_xor(vz, o); cnt += __shfl_xor(cnt, o);
    }
    if (l == 0){
      float* wr = misc + 16 + w*4;
      wr[0] = vx; wr[1] = vy; wr[2] = vz; wr[3] = cnt;
    }
  }
  __syncthreads();
  if (t == 0){
    float sx=0.f, sy=0.f, sz=0.f, sc=0.f;
    #pragma unroll
    for (int ww = 0; ww < 8; ++ww){
      sx += misc[16+ww*4]; sy += misc[16+ww*4+1];
      sz += misc[16+ww*4+2]; sc += misc[16+ww*4+3];
    }
    const float d = sc + 1e-7f, fm = (float)fmask[bi];
    coor_out[bi*3+0] = sx/d*fm; coor_out[bi*3+1] = sy/d*fm; coor_out[bi*3+2] = sz/d*fm;
  }

  {
    float* part = (float*)(smem + L_PART);
    const int c8 = t & 31, jg = t >> 5;
    const int ch0 = 256 + c8*8;
    const int h = (c8 < 16) ? (c8 >> 1) : ((c8 - 16) >> 1);
    const int slot0 = (c8 < 16) ? (h*32 + (c8 & 1)*8) : (h*32 + 16 + (c8 & 1)*8);
    float a8[8];
    #pragma unroll
    for (int e = 0; e < 8; ++e) a8[e] = 0.f;
    for (int q = 0; q < 24; ++q){
      const int j = jg*24 + q;
      const float p = att[j*8 + h];
      uint4 v = *(const uint4*)&qkbf[(size_t)(b*N_+j)*512 + ch0];
      const u16* vp = (const u16*)&v;
      #pragma unroll
      for (int e = 0; e < 8; ++e) a8[e] = fmaf(p, bf2f(vp[e]), a8[e]);
    }
    float4 o0 = {a8[0],a8[1],a8[2],a8[3]}, o1 = {a8[4],a8[5],a8[6],a8[7]};
    *(float4*)&part[jg*256 + slot0]     = o0;
    *(float4*)&part[jg*256 + slot0 + 4] = o1;
  }
  __syncthreads();
  {
    float* part = (float*)(smem + L_PART);
    float* red2 = (float*)(smem + L_RED2);
    if (t < 256){
      float s = 0.f;
      #pragma unroll
      for (int g = 0; g < 16; ++g) s += part[g*256 + t];
      red2[t] = s;
    }
  }
  __syncthreads();
  {
    float* part = (float*)(smem + L_PART);
    float* red2 = (float*)(smem + L_RED2);
    const int c = t & 127, qq = t >> 7;
    float s = 0.f;
    #pragma unroll 4
    for (int k = qq*64; k < qq*64 + 64; ++k)
      s = fmaf(red2[k], Wnode[(size_t)k*128 + c], s);
    part[qq*128 + c] = s;
    __syncthreads();
    if (t < 128)
      node_out[(size_t)bi*128 + t] = part[t] + part[128+t] + part[256+t] + part[384+t] + bnode[t];
  }
}

extern "C" void kernel_launch(void* const* d_in, const int* in_sizes, int n_in,
                              void* d_out, int out_size, void* d_ws, size_t ws_size,
                              hipStream_t stream)
{
  const float* x     = (const float*)d_in[0];
  const float* coor  = (const float*)d_in[1];
  const float* eattr = (const float*)d_in[2];
  const float* Wqk   = (const float*)d_in[3];
  const float* bqk   = (const float*)d_in[4];
  const float* We    = (const float*)d_in[5];
  const float* be    = (const float*)d_in[6];
  const float* Wnode = (const float*)d_in[7];
  const float* bnode = (const float*)d_in[8];
  const float* Wedge = (const float*)d_in[9];
  const float* bedge = (const float*)d_in[10];
  const float* Wc1   = (const float*)d_in[11];
  const float* bc1   = (const float*)d_in[12];
  const float* Wc2   = (const float*)d_in[13];
  const float* bc2   = (const float*)d_in[14];
  const int*   emask = (const int*)d_in[15];
  const int*   fmask = (const int*)d_in[16];

  u16* qkbf = (u16*)d_ws;                         // 786432 B

  float* out      = (float*)d_out;
  float* node_out = out;                           // 2*384*128
  float* edge_out = out + 98304;                   // 2*384*384*64
  float* coor_out = out + 98304 + 18874368;        // 2*384*3

  const size_t NEED = 6799360;
  if (ws_size >= NEED){
    u16*   WeF   = (u16*)((char*)d_ws + 786432);   // 65536
    u16*   WgF   = (u16*)((char*)d_ws + 851968);   // 16384
    u16*   W1F   = (u16*)((char*)d_ws + 868352);   // 32768
    u16*   attL  = (u16*)((char*)d_ws + 901120);   // 4718592
    float* cattB = (float*)((char*)d_ws + 5619712);// 1179648

    prep_frag<<<dim3(28), dim3(256), 0, stream>>>(We, Wedge, Wc1, WeF, WgF, W1F);
    qk_kernel<<<dim3(192), dim3(256), 0, stream>>>(x, Wqk, bqk, qkbf);
    k1L_logits_ev<<<dim3(3, NB), dim3(256), 0, stream>>>(
        coor, eattr, be, emask, qkbf, WeF, attL, (u16*)edge_out);
    k2_softmax<<<dim3(NB), dim3(512), 0, stream>>>(attL);
    k3L_edge_c1<<<dim3(6, NB), dim3(256), 0, stream>>>(
        bedge, bc1, Wc2, qkbf, WgF, W1F, attL, edge_out, cattB);
    k4_node_coor<<<dim3(NB), dim3(256), 0, stream>>>(
        coor, Wnode, bnode, bc2, emask, fmask, qkbf, attL, cattB, node_out, coor_out);
  } else {
    u16* WeT  = (u16*)((char*)d_ws + 786432);
    u16* WgT  = (u16*)((char*)d_ws + 851968);
    u16* Wc1T = (u16*)((char*)d_ws + 868352);
    prep_wt<<<dim3(14), dim3(512), 0, stream>>>(We, Wedge, Wc1, WeT, WgT, Wc1T);
    qk_kernel<<<dim3(192), dim3(256), 0, stream>>>(x, Wqk, bqk, qkbf);
    se3_fused<<<dim3(NB), dim3(512), L_TOTAL, stream>>>(
        coor, eattr, be, bedge, Wnode, bnode, bc1, Wc2, bc2,
        emask, fmask, qkbf, WeT, WgT, Wc1T, node_out, edge_out, coor_out);
  }
}